// Round 4
// baseline (3736.134 us; speedup 1.0000x reference)
//
#include <hip/hip_runtime.h>

#define N_TOTAL 150000   // N_USERS + M_ITEMS
#define DIM 64
#define NBUCK 512
#define BSHIFT 9         // 512 rows per bucket -> cs region ~131 KB (L2-hot)
#define CHUNK 4096       // edges per bin block (256 thr x 16)

// ---- CSR build ----

__global__ void hist_kernel(const int* __restrict__ rows, int* __restrict__ cnt, int nnz) {
    int t = blockIdx.x * blockDim.x + threadIdx.x;
    if (t < nnz) atomicAdd(&cnt[rows[t]], 1);
}

// Hierarchical exclusive scan, step 1: per-block (1024 elems, 256 thr x 4).
__global__ void scan_block_kernel(const int* __restrict__ cnt, int* __restrict__ excl,
                                  int* __restrict__ bsum, int n) {
    __shared__ int sh[256];
    int t = threadIdx.x;
    int i0 = blockIdx.x * 1024 + t * 4;
    int v0 = (i0 + 0 < n) ? cnt[i0 + 0] : 0;
    int v1 = (i0 + 1 < n) ? cnt[i0 + 1] : 0;
    int v2 = (i0 + 2 < n) ? cnt[i0 + 2] : 0;
    int v3 = (i0 + 3 < n) ? cnt[i0 + 3] : 0;
    int s = v0 + v1 + v2 + v3;
    sh[t] = s;
    __syncthreads();
    for (int off = 1; off < 256; off <<= 1) {
        int x = (t >= off) ? sh[t - off] : 0;
        __syncthreads();
        sh[t] += x;
        __syncthreads();
    }
    int myexcl = sh[t] - s;
    if (t == 255) bsum[blockIdx.x] = sh[255];
    if (i0 + 0 < n) excl[i0 + 0] = myexcl;
    if (i0 + 1 < n) excl[i0 + 1] = myexcl + v0;
    if (i0 + 2 < n) excl[i0 + 2] = myexcl + v0 + v1;
    if (i0 + 3 < n) excl[i0 + 3] = myexcl + v0 + v1 + v2;
}

// step 2: exclusive scan of block sums (nb <= 256) in place.
__global__ void scan_tops_kernel(int* __restrict__ bsum, int nb) {
    __shared__ int sh[256];
    int t = threadIdx.x;
    int v = (t < nb) ? bsum[t] : 0;
    sh[t] = v;
    __syncthreads();
    for (int off = 1; off < 256; off <<= 1) {
        int x = (t >= off) ? sh[t - off] : 0;
        __syncthreads();
        sh[t] += x;
        __syncthreads();
    }
    if (t < nb) bsum[t] = sh[t] - v;
}

// step 3: add block offsets.
__global__ void scan_add_kernel(int* __restrict__ excl, const int* __restrict__ bsum, int n) {
    int i = blockIdx.x * blockDim.x + threadIdx.x;
    if (i < n) excl[i] += bsum[i >> 10];
}

// bucket region starts in edge space (from the exclusive row scan, pre-mutation)
__global__ void binit_kernel(const int* __restrict__ rstart, int* __restrict__ binit,
                             int* __restrict__ bcur, int nnz) {
    int t = blockIdx.x * blockDim.x + threadIdx.x;
    if (t > NBUCK) return;
    int r = t << BSHIFT;
    int v = (r < N_TOTAL) ? rstart[r] : nnz;
    binit[t] = v;
    if (t < NBUCK) bcur[t] = v;
}

// Phase B: LDS multisplit into NBUCK row-range buckets; contiguous int4 runs
// per (block,bucket) -> ~1x HBM write amplification.
__global__ void bin_kernel(const int* __restrict__ idx, const float* __restrict__ val,
                           int* __restrict__ bcur, int4* __restrict__ binned, int nnz) {
    __shared__ int lcnt[NBUCK];
    __shared__ int lbase[NBUCK];
    int t = threadIdx.x;
    int base = blockIdx.x * CHUNK;
    for (int b = t; b < NBUCK; b += 256) lcnt[b] = 0;
    __syncthreads();
    int rows[16];
    #pragma unroll
    for (int i = 0; i < 16; ++i) {
        int e = base + t + i * 256;
        int r = (e < nnz) ? idx[e] : -1;
        rows[i] = r;
        if (r >= 0) atomicAdd(&lcnt[r >> BSHIFT], 1);
    }
    __syncthreads();
    for (int b = t; b < NBUCK; b += 256) {
        int c = lcnt[b];
        lbase[b] = c ? atomicAdd(&bcur[b], c) : 0;
        lcnt[b] = 0;     // reuse as intra-block offset
    }
    __syncthreads();
    #pragma unroll
    for (int i = 0; i < 16; ++i) {
        int r = rows[i];
        if (r >= 0) {
            int e = base + t + i * 256;
            int b = r >> BSHIFT;
            int o = atomicAdd(&lcnt[b], 1);
            int4 pk;
            pk.x = r;
            pk.y = idx[nnz + e];
            pk.z = __float_as_int(val[e]);
            pk.w = 0;
            binned[lbase[b] + o] = pk;
        }
    }
}

// Phase C: exact-position scatter within one bucket's L2-hot ~131KB region.
// atomicAdd on rstart turns it into row END (inclusive scan); spmm recovers start.
__global__ void scatterc_kernel(const int4* __restrict__ binned, const int* __restrict__ binit,
                                int* __restrict__ rstart, float2* __restrict__ cs) {
    int b = blockIdx.x >> 1;
    int half = blockIdx.x & 1;
    int s = binit[b], e = binit[b + 1];
    int mid = s + ((e - s) >> 1);
    int lo = half ? mid : s;
    int hi = half ? e : mid;
    for (int k = lo + (int)threadIdx.x; k < hi; k += 256) {
        int4 pk = binned[k];
        int pos = atomicAdd(&rstart[pk.x], 1);
        float2 ed;
        ed.x = __int_as_float(pk.y);
        ed.y = __int_as_float(pk.z);
        cs[pos] = ed;
    }
}

// ---- out = sum_f (w[f]/4) * emb_f  (layer-0 contribution of all 3 factors) ----
__global__ void init_out_kernel(const float* __restrict__ e0, const float* __restrict__ e1,
                                const float* __restrict__ e2, const float* __restrict__ w,
                                float* __restrict__ out, int n4) {
    int i = blockIdx.x * blockDim.x + threadIdx.x;
    if (i >= n4) return;
    float c0 = w[0] * 0.25f, c1 = w[1] * 0.25f, c2 = w[2] * 0.25f;
    float4 a = reinterpret_cast<const float4*>(e0)[i];
    float4 b = reinterpret_cast<const float4*>(e1)[i];
    float4 c = reinterpret_cast<const float4*>(e2)[i];
    float4 o;
    o.x = c0 * a.x + c1 * b.x + c2 * c.x;
    o.y = c0 * a.y + c1 * b.y + c2 * c.y;
    o.z = c0 * a.z + c1 * b.z + c2 * c.z;
    o.w = c0 * a.w + c1 * b.w + c2 * c.w;
    reinterpret_cast<float4*>(out)[i] = o;
}

// ---- pull SpMM: one 64-lane wave per row; lane d owns dim d.
//      rend[row] = end (start = end - cnt).  out[row] += (w[f]/4)*acc fused.
//      LAST: final layer of a factor -> y is not needed, skip the store.
template <bool LAST>
__global__ void spmm_csr_kernel(const int* __restrict__ rend, const int* __restrict__ cnt,
                                const float2* __restrict__ cs,
                                const float* __restrict__ x, float* __restrict__ y,
                                float* __restrict__ out, const float* __restrict__ w, int f,
                                int nrows) {
    int gid = blockIdx.x * blockDim.x + threadIdx.x;
    int row = gid >> 6;
    int lane = gid & 63;
    if (row >= nrows) return;
    int e = rend[row];
    int c = cnt[row];
    int s = e - c;
    float acc0 = 0.f, acc1 = 0.f;
    int k = s;
    for (; k + 1 < e; k += 2) {
        float2 e0 = cs[k];
        float2 e1 = cs[k + 1];
        acc0 += e0.y * x[((size_t)__float_as_int(e0.x) << 6) + lane];
        acc1 += e1.y * x[((size_t)__float_as_int(e1.x) << 6) + lane];
    }
    if (k < e) {
        float2 e0 = cs[k];
        acc0 += e0.y * x[((size_t)__float_as_int(e0.x) << 6) + lane];
    }
    float acc = acc0 + acc1;
    size_t o = ((size_t)row << 6) + lane;
    if (!LAST) y[o] = acc;
    out[o] += w[f] * 0.25f * acc;
}

extern "C" void kernel_launch(void* const* d_in, const int* in_sizes, int n_in,
                              void* d_out, int out_size, void* d_ws, size_t ws_size,
                              hipStream_t stream) {
    const float* emb[3]  = {(const float*)d_in[0], (const float*)d_in[1], (const float*)d_in[2]};
    const int*   gidx[3] = {(const int*)d_in[3],   (const int*)d_in[5],   (const int*)d_in[7]};
    const float* gval[3] = {(const float*)d_in[4], (const float*)d_in[6], (const float*)d_in[8]};
    const float* w = (const float*)d_in[9];
    float* out = (float*)d_out;

    const int nnz = in_sizes[4];
    const size_t bufElems = (size_t)N_TOTAL * DIM;   // 9.6M floats

    // ws layout (binned int4 aliases bufA+bufB: 76.8MB, dead before spmm writes)
    float*  bufA   = (float*)d_ws;                   // 38.4 MB
    float*  bufB   = bufA + bufElems;                // 38.4 MB
    int4*   binned = (int4*)d_ws;                    // 76.8 MB (alias A+B)
    float2* cs     = (float2*)(bufB + bufElems);     // 38.4 MB (packed col,val)
    int*    cnt    = (int*)(cs + nnz);               // 600 KB
    int*    rstart = cnt + N_TOTAL;                  // 600 KB
    int*    bsum   = rstart + N_TOTAL;               // ~1 KB (147)
    int*    bcur   = bsum + 256;                     // 2 KB
    int*    binit  = bcur + NBUCK;                   // 2 KB (513)

    const int n4 = (int)(bufElems / 4);
    const int nScanBlocks = (N_TOTAL + 1023) / 1024;  // 147
    dim3 eltGrid((n4 + 255) / 256);
    dim3 edgeGrid((nnz + 255) / 256);
    dim3 binGrid((nnz + CHUNK - 1) / CHUNK);          // 1172
    dim3 rowGrid((unsigned)(((size_t)N_TOTAL * 64 + 255) / 256));
    dim3 addGrid((N_TOTAL + 255) / 256);

    // layer-0 contributions of all factors in one pass
    init_out_kernel<<<eltGrid, 256, 0, stream>>>(emb[0], emb[1], emb[2], w, out, n4);

    for (int f = 0; f < 3; ++f) {
        // --- build CSR for this factor's graph ---
        hipMemsetAsync(cnt, 0, N_TOTAL * sizeof(int), stream);
        hist_kernel<<<edgeGrid, 256, 0, stream>>>(gidx[f], cnt, nnz);
        scan_block_kernel<<<nScanBlocks, 256, 0, stream>>>(cnt, rstart, bsum, N_TOTAL);
        scan_tops_kernel<<<1, 256, 0, stream>>>(bsum, nScanBlocks);
        scan_add_kernel<<<addGrid, 256, 0, stream>>>(rstart, bsum, N_TOTAL);
        binit_kernel<<<3, 256, 0, stream>>>(rstart, binit, bcur, nnz);
        bin_kernel<<<binGrid, 256, 0, stream>>>(gidx[f], gval[f], bcur, binned, nnz);
        scatterc_kernel<<<NBUCK * 2, 256, 0, stream>>>(binned, binit, rstart, cs);

        // --- 3 propagation layers, axpy fused into SpMM epilogue ---
        spmm_csr_kernel<false><<<rowGrid, 256, 0, stream>>>(rstart, cnt, cs, emb[f], bufA,
                                                            out, w, f, N_TOTAL);
        spmm_csr_kernel<false><<<rowGrid, 256, 0, stream>>>(rstart, cnt, cs, bufA, bufB,
                                                            out, w, f, N_TOTAL);
        spmm_csr_kernel<true><<<rowGrid, 256, 0, stream>>>(rstart, cnt, cs, bufB, nullptr,
                                                           out, w, f, N_TOTAL);
    }
}

// Round 5
// 2098.925 us; speedup vs baseline: 1.7800x; 1.7800x over previous
//
#include <hip/hip_runtime.h>
#include <hip/hip_fp16.h>

#define N_TOTAL 150000   // N_USERS + M_ITEMS
#define DIM 64
#define RPB 256          // rows per bucket (pow2)
#define NBUCK 586        // ceil(150000/256)
#define CHUNK 4096       // edges per binning block (256 thr x 16)

// ---- bucket-level histogram (LDS-aggregated) ----
__global__ void bucket_hist_kernel(const int* __restrict__ rows, int* __restrict__ bcnt, int nnz) {
    __shared__ int l[NBUCK];
    for (int b = threadIdx.x; b < NBUCK; b += 256) l[b] = 0;
    __syncthreads();
    int base = blockIdx.x * CHUNK;
    #pragma unroll
    for (int i = 0; i < 16; ++i) {
        int e = base + (int)threadIdx.x + i * 256;
        if (e < nnz) atomicAdd(&l[rows[e] >> 8], 1);
    }
    __syncthreads();
    for (int b = threadIdx.x; b < NBUCK; b += 256) {
        int c = l[b];
        if (c) atomicAdd(&bcnt[b], c);
    }
}

// exclusive scan of up to 1024 ints by one 256-thread block
__global__ void scan_block_kernel(const int* __restrict__ cnt, int* __restrict__ excl,
                                  int* __restrict__ bsum, int n) {
    __shared__ int sh[256];
    int t = threadIdx.x;
    int i0 = t * 4;
    int v0 = (i0 + 0 < n) ? cnt[i0 + 0] : 0;
    int v1 = (i0 + 1 < n) ? cnt[i0 + 1] : 0;
    int v2 = (i0 + 2 < n) ? cnt[i0 + 2] : 0;
    int v3 = (i0 + 3 < n) ? cnt[i0 + 3] : 0;
    int s = v0 + v1 + v2 + v3;
    sh[t] = s;
    __syncthreads();
    for (int off = 1; off < 256; off <<= 1) {
        int x = (t >= off) ? sh[t - off] : 0;
        __syncthreads();
        sh[t] += x;
        __syncthreads();
    }
    int myexcl = sh[t] - s;
    if (t == 255) bsum[0] = sh[255];
    if (i0 + 0 < n) excl[i0 + 0] = myexcl;
    if (i0 + 1 < n) excl[i0 + 1] = myexcl + v0;
    if (i0 + 2 < n) excl[i0 + 2] = myexcl + v0 + v1;
    if (i0 + 3 < n) excl[i0 + 3] = myexcl + v0 + v1 + v2;
}

__global__ void binit_kernel(int* __restrict__ bbase, int* __restrict__ bcur, int nnz) {
    int t = blockIdx.x * 256 + threadIdx.x;
    if (t < NBUCK) bcur[t] = bbase[t];
    if (t == NBUCK) bbase[NBUCK] = nnz;
}

// Phase B: LDS multisplit into NBUCK row-range buckets; packed 8B records,
// contiguous runs per (block,bucket) -> ~1x HBM write amplification.
// pk.x = rowLocal(8b)<<18 | col(18b) ; pk.y = f32 val bits
__global__ void bin_kernel(const int* __restrict__ idx, const float* __restrict__ val,
                           int* __restrict__ bcur, uint2* __restrict__ binned, int nnz) {
    __shared__ int lcnt[NBUCK];
    __shared__ int lbase[NBUCK];
    int t = threadIdx.x;
    int base = blockIdx.x * CHUNK;
    for (int b = t; b < NBUCK; b += 256) lcnt[b] = 0;
    __syncthreads();
    int rows[16];
    #pragma unroll
    for (int i = 0; i < 16; ++i) {
        int e = base + t + i * 256;
        int r = (e < nnz) ? idx[e] : -1;
        rows[i] = r;
        if (r >= 0) atomicAdd(&lcnt[r >> 8], 1);
    }
    __syncthreads();
    for (int b = t; b < NBUCK; b += 256) {
        int c = lcnt[b];
        lbase[b] = c ? atomicAdd(&bcur[b], c) : 0;
        lcnt[b] = 0;     // reuse as intra-block offset
    }
    __syncthreads();
    #pragma unroll
    for (int i = 0; i < 16; ++i) {
        int r = rows[i];
        if (r >= 0) {
            int e = base + t + i * 256;
            int b = r >> 8;
            int o = atomicAdd(&lcnt[b], 1);
            uint2 pk;
            pk.x = ((unsigned)(r & 255) << 18) | (unsigned)idx[nnz + e];
            pk.y = __float_as_uint(val[e]);
            binned[lbase[b] + o] = pk;
        }
    }
}

// Phase C: per-bucket exact CSR placement. LDS row-hist + LDS scan gives the
// per-row offsets (rlo/rhi written here); writes land in one L2-hot ~65KB run.
__global__ void scatterc_kernel(const uint2* __restrict__ binned, const int* __restrict__ bbase,
                                int* __restrict__ rlo, int* __restrict__ rhi,
                                float2* __restrict__ cs) {
    __shared__ int hist[RPB];
    __shared__ int cur[RPB];
    int b = blockIdx.x;
    int s = bbase[b], e = bbase[b + 1];
    int t = threadIdx.x;
    hist[t] = 0;
    __syncthreads();
    for (int k = s + t; k < e; k += 256)
        atomicAdd(&hist[binned[k].x >> 18], 1);
    __syncthreads();
    int v = hist[t];
    cur[t] = v;
    __syncthreads();
    for (int off = 1; off < 256; off <<= 1) {
        int x = (t >= off) ? cur[t - off] : 0;
        __syncthreads();
        cur[t] += x;
        __syncthreads();
    }
    int excl = cur[t] - v;
    int row = (b << 8) + t;
    if (row < N_TOTAL) { rlo[row] = s + excl; rhi[row] = s + excl + v; }
    cur[t] = excl;
    __syncthreads();
    for (int k = s + t; k < e; k += 256) {
        uint2 ed = binned[k];
        int rl = ed.x >> 18;
        int o = atomicAdd(&cur[rl], 1);
        float2 c;
        c.x = __int_as_float((int)(ed.x & 0x3FFFF));
        c.y = __uint_as_float(ed.y);
        cs[s + o] = c;
    }
}

// ---- out = sum_f (w[f]/4) * emb_f ----
__global__ void init_out_kernel(const float* __restrict__ e0, const float* __restrict__ e1,
                                const float* __restrict__ e2, const float* __restrict__ w,
                                float* __restrict__ out, int n4) {
    int i = blockIdx.x * blockDim.x + threadIdx.x;
    if (i >= n4) return;
    float c0 = w[0] * 0.25f, c1 = w[1] * 0.25f, c2 = w[2] * 0.25f;
    float4 a = reinterpret_cast<const float4*>(e0)[i];
    float4 b = reinterpret_cast<const float4*>(e1)[i];
    float4 c = reinterpret_cast<const float4*>(e2)[i];
    float4 o;
    o.x = c0 * a.x + c1 * b.x + c2 * c.x;
    o.y = c0 * a.y + c1 * b.y + c2 * c.y;
    o.z = c0 * a.z + c1 * b.z + c2 * c.z;
    o.w = c0 * a.w + c1 * b.w + c2 * c.w;
    reinterpret_cast<float4*>(out)[i] = o;
}

// f32 -> f16 table conversion
__global__ void conv_f16_kernel(const float* __restrict__ x, __half2* __restrict__ y, int n4) {
    int i = blockIdx.x * blockDim.x + threadIdx.x;
    if (i >= n4) return;
    float4 v = reinterpret_cast<const float4*>(x)[i];
    y[2 * i + 0] = __floats2half2_rn(v.x, v.y);
    y[2 * i + 1] = __floats2half2_rn(v.z, v.w);
}

// ---- pull SpMM, fp16 gather table: one wave per row, 32 lanes x half2 per
// edge, two edges per wave-step.  out[row] += (w[f]/4)*acc fused. ----
template <bool LAST>
__global__ void spmm_f16_kernel(const int* __restrict__ rlo, const int* __restrict__ rhi,
                                const float2* __restrict__ cs, const __half2* __restrict__ x,
                                __half2* __restrict__ y, float* __restrict__ out,
                                const float* __restrict__ w, int f, int nrows) {
    int gid = blockIdx.x * blockDim.x + threadIdx.x;
    int row = gid >> 6;
    int lane = gid & 63;
    if (row >= nrows) return;
    int s = rlo[row], e = rhi[row];
    int half = lane >> 5, sub = lane & 31;
    float ax = 0.f, ay = 0.f, bx = 0.f, by = 0.f;
    int k = s + half;
    for (; k + 2 < e; k += 4) {
        float2 e0 = cs[k];
        float2 e1 = cs[k + 2];
        __half2 h0 = x[((size_t)__float_as_int(e0.x) << 5) + sub];
        __half2 h1 = x[((size_t)__float_as_int(e1.x) << 5) + sub];
        float2 f0 = __half22float2(h0);
        float2 f1 = __half22float2(h1);
        ax += e0.y * f0.x; ay += e0.y * f0.y;
        bx += e1.y * f1.x; by += e1.y * f1.y;
    }
    for (; k < e; k += 2) {
        float2 e0 = cs[k];
        __half2 h0 = x[((size_t)__float_as_int(e0.x) << 5) + sub];
        float2 f0 = __half22float2(h0);
        ax += e0.y * f0.x; ay += e0.y * f0.y;
    }
    ax += bx; ay += by;
    ax += __shfl_xor(ax, 32);
    ay += __shfl_xor(ay, 32);
    if (half == 0) {
        size_t o = ((size_t)row << 5) + sub;
        if (!LAST) y[o] = __floats2half2_rn(ax, ay);
        float c = w[f] * 0.25f;
        float2* o2 = reinterpret_cast<float2*>(out);
        float2 cv = o2[o];
        cv.x += c * ax;
        cv.y += c * ay;
        o2[o] = cv;
    }
}

extern "C" void kernel_launch(void* const* d_in, const int* in_sizes, int n_in,
                              void* d_out, int out_size, void* d_ws, size_t ws_size,
                              hipStream_t stream) {
    const float* emb[3]  = {(const float*)d_in[0], (const float*)d_in[1], (const float*)d_in[2]};
    const int*   gidx[3] = {(const int*)d_in[3],   (const int*)d_in[5],   (const int*)d_in[7]};
    const float* gval[3] = {(const float*)d_in[4], (const float*)d_in[6], (const float*)d_in[8]};
    const float* w = (const float*)d_in[9];
    float* out = (float*)d_out;

    const int nnz = in_sizes[4];
    const size_t bufElems = (size_t)N_TOTAL * DIM;       // 9.6M
    const size_t f16Bytes = bufElems * 2;                // 19.2 MB

    // ws layout:
    //   [0, 38.4MB)      binned (uint2)  -- aliased with {emb16, bufA16}
    //   [38.4, 57.6MB)   bufB16
    //   [57.6, 96MB)     cs (float2)
    //   then rlo, rhi, bcnt, bbase, bcur, bsum
    char* base = (char*)d_ws;
    uint2*   binned = (uint2*)base;
    __half2* emb16  = (__half2*)base;                    // alias: live after scatterc
    __half2* bufA16 = (__half2*)(base + f16Bytes);       // alias: live after spmm layer 1
    __half2* bufB16 = (__half2*)(base + 2 * f16Bytes);
    float2*  cs     = (float2*)(base + 3 * f16Bytes);
    int*     rlo    = (int*)(base + 3 * f16Bytes + (size_t)nnz * 8);
    int*     rhi    = rlo + N_TOTAL;
    int*     bcnt   = rhi + N_TOTAL;
    int*     bbase  = bcnt + NBUCK;        // NBUCK+1
    int*     bcur   = bbase + NBUCK + 1;
    int*     bsum   = bcur + NBUCK;

    const int n4 = (int)(bufElems / 4);
    dim3 eltGrid((n4 + 255) / 256);
    dim3 chunkGrid((nnz + CHUNK - 1) / CHUNK);            // 1172
    dim3 rowGrid((unsigned)(((size_t)N_TOTAL * 64 + 255) / 256));

    // layer-0 contributions of all factors in one pass
    init_out_kernel<<<eltGrid, 256, 0, stream>>>(emb[0], emb[1], emb[2], w, out, n4);

    for (int f = 0; f < 3; ++f) {
        // --- bucket CSR build ---
        hipMemsetAsync(bcnt, 0, NBUCK * sizeof(int), stream);
        bucket_hist_kernel<<<chunkGrid, 256, 0, stream>>>(gidx[f], bcnt, nnz);
        scan_block_kernel<<<1, 256, 0, stream>>>(bcnt, bbase, bsum, NBUCK);
        binit_kernel<<<3, 256, 0, stream>>>(bbase, bcur, nnz);
        bin_kernel<<<chunkGrid, 256, 0, stream>>>(gidx[f], gval[f], bcur, binned, nnz);
        scatterc_kernel<<<NBUCK, 256, 0, stream>>>(binned, bbase, rlo, rhi, cs);

        // --- fp16 copy of this factor's embedding (binned is dead now) ---
        conv_f16_kernel<<<eltGrid, 256, 0, stream>>>(emb[f], emb16, n4);

        // --- 3 propagation layers, axpy fused into SpMM epilogue ---
        spmm_f16_kernel<false><<<rowGrid, 256, 0, stream>>>(rlo, rhi, cs, emb16, bufA16,
                                                            out, w, f, N_TOTAL);
        spmm_f16_kernel<false><<<rowGrid, 256, 0, stream>>>(rlo, rhi, cs, bufA16, bufB16,
                                                            out, w, f, N_TOTAL);
        spmm_f16_kernel<true><<<rowGrid, 256, 0, stream>>>(rlo, rhi, cs, bufB16, nullptr,
                                                           out, w, f, N_TOTAL);
    }
}

// Round 6
// 1721.395 us; speedup vs baseline: 2.1704x; 1.2193x over previous
//
#include <hip/hip_runtime.h>
#include <hip/hip_fp16.h>

#define N_TOTAL 150000   // N_USERS + M_ITEMS
#define DIM 64
#define RPB 256          // rows per bucket (pow2)
#define NBUCK 586        // ceil(150000/256)
#define CHUNK 8192       // edges per binning block (512 thr x 16)

// ---- bucket-level histogram (LDS-aggregated) ----
__global__ void bucket_hist_kernel(const int* __restrict__ rows, int* __restrict__ bcnt, int nnz) {
    __shared__ int l[NBUCK];
    for (int b = threadIdx.x; b < NBUCK; b += 512) l[b] = 0;
    __syncthreads();
    int base = blockIdx.x * CHUNK;
    #pragma unroll
    for (int i = 0; i < 16; ++i) {
        int e = base + (int)threadIdx.x + i * 512;
        if (e < nnz) atomicAdd(&l[rows[e] >> 8], 1);
    }
    __syncthreads();
    for (int b = threadIdx.x; b < NBUCK; b += 512) {
        int c = l[b];
        if (c) atomicAdd(&bcnt[b], c);
    }
}

// exclusive scan of up to 1024 ints by one 256-thread block
__global__ void scan_block_kernel(const int* __restrict__ cnt, int* __restrict__ excl,
                                  int* __restrict__ bsum, int n) {
    __shared__ int sh[256];
    int t = threadIdx.x;
    int i0 = t * 4;
    int v0 = (i0 + 0 < n) ? cnt[i0 + 0] : 0;
    int v1 = (i0 + 1 < n) ? cnt[i0 + 1] : 0;
    int v2 = (i0 + 2 < n) ? cnt[i0 + 2] : 0;
    int v3 = (i0 + 3 < n) ? cnt[i0 + 3] : 0;
    int s = v0 + v1 + v2 + v3;
    sh[t] = s;
    __syncthreads();
    for (int off = 1; off < 256; off <<= 1) {
        int x = (t >= off) ? sh[t - off] : 0;
        __syncthreads();
        sh[t] += x;
        __syncthreads();
    }
    int myexcl = sh[t] - s;
    if (t == 255) bsum[0] = sh[255];
    if (i0 + 0 < n) excl[i0 + 0] = myexcl;
    if (i0 + 1 < n) excl[i0 + 1] = myexcl + v0;
    if (i0 + 2 < n) excl[i0 + 2] = myexcl + v0 + v1;
    if (i0 + 3 < n) excl[i0 + 3] = myexcl + v0 + v1 + v2;
}

__global__ void binit_kernel(int* __restrict__ bbase, int* __restrict__ bcur, int nnz) {
    int t = blockIdx.x * 256 + threadIdx.x;
    if (t < NBUCK) bcur[t] = bbase[t];
    if (t == NBUCK) bbase[NBUCK] = nnz;
}

// Phase B: LDS multisplit into NBUCK row-range buckets; packed 8B records,
// contiguous runs per (block,bucket).  CHUNK=8192 -> avg run 14 edges = 112B.
// pk.x = rowLocal(8b)<<18 | col(18b) ; pk.y = f32 val bits
__global__ void bin_kernel(const int* __restrict__ idx, const float* __restrict__ val,
                           int* __restrict__ bcur, uint2* __restrict__ binned, int nnz) {
    __shared__ int lcnt[NBUCK];
    __shared__ int lbase[NBUCK];
    int t = threadIdx.x;
    int base = blockIdx.x * CHUNK;
    for (int b = t; b < NBUCK; b += 512) lcnt[b] = 0;
    __syncthreads();
    int rows[16];
    #pragma unroll
    for (int i = 0; i < 16; ++i) {
        int e = base + t + i * 512;
        int r = (e < nnz) ? idx[e] : -1;
        rows[i] = r;
        if (r >= 0) atomicAdd(&lcnt[r >> 8], 1);
    }
    __syncthreads();
    for (int b = t; b < NBUCK; b += 512) {
        int c = lcnt[b];
        lbase[b] = c ? atomicAdd(&bcur[b], c) : 0;
        lcnt[b] = 0;     // reuse as intra-block offset
    }
    __syncthreads();
    #pragma unroll
    for (int i = 0; i < 16; ++i) {
        int r = rows[i];
        if (r >= 0) {
            int e = base + t + i * 512;
            int b = r >> 8;
            int o = atomicAdd(&lcnt[b], 1);
            uint2 pk;
            pk.x = ((unsigned)(r & 255) << 18) | (unsigned)idx[nnz + e];
            pk.y = __float_as_uint(val[e]);
            binned[lbase[b] + o] = pk;
        }
    }
}

// Phase C: per-bucket exact CSR placement. LDS row-hist + LDS scan gives the
// per-row offsets (rlo/rhi written here); writes land in one L2-hot ~65KB run.
__global__ void scatterc_kernel(const uint2* __restrict__ binned, const int* __restrict__ bbase,
                                int* __restrict__ rlo, int* __restrict__ rhi,
                                float2* __restrict__ cs) {
    __shared__ int hist[RPB];
    __shared__ int cur[RPB];
    int b = blockIdx.x;
    int s = bbase[b], e = bbase[b + 1];
    int t = threadIdx.x;
    hist[t] = 0;
    __syncthreads();
    for (int k = s + t; k < e; k += 256)
        atomicAdd(&hist[binned[k].x >> 18], 1);
    __syncthreads();
    int v = hist[t];
    cur[t] = v;
    __syncthreads();
    for (int off = 1; off < 256; off <<= 1) {
        int x = (t >= off) ? cur[t - off] : 0;
        __syncthreads();
        cur[t] += x;
        __syncthreads();
    }
    int excl = cur[t] - v;
    int row = (b << 8) + t;
    if (row < N_TOTAL) { rlo[row] = s + excl; rhi[row] = s + excl + v; }
    cur[t] = excl;
    __syncthreads();
    for (int k = s + t; k < e; k += 256) {
        uint2 ed = binned[k];
        int rl = ed.x >> 18;
        int o = atomicAdd(&cur[rl], 1);
        float2 c;
        c.x = __int_as_float((int)(ed.x & 0x3FFFF));
        c.y = __uint_as_float(ed.y);
        cs[s + o] = c;
    }
}

// ---- out = sum_f (w[f]/4) * emb_f ----
__global__ void init_out_kernel(const float* __restrict__ e0, const float* __restrict__ e1,
                                const float* __restrict__ e2, const float* __restrict__ w,
                                float* __restrict__ out, int n4) {
    int i = blockIdx.x * blockDim.x + threadIdx.x;
    if (i >= n4) return;
    float c0 = w[0] * 0.25f, c1 = w[1] * 0.25f, c2 = w[2] * 0.25f;
    float4 a = reinterpret_cast<const float4*>(e0)[i];
    float4 b = reinterpret_cast<const float4*>(e1)[i];
    float4 c = reinterpret_cast<const float4*>(e2)[i];
    float4 o;
    o.x = c0 * a.x + c1 * b.x + c2 * c.x;
    o.y = c0 * a.y + c1 * b.y + c2 * c.y;
    o.z = c0 * a.z + c1 * b.z + c2 * c.z;
    o.w = c0 * a.w + c1 * b.w + c2 * c.w;
    reinterpret_cast<float4*>(out)[i] = o;
}

// f32 -> f16 table conversion
__global__ void conv_f16_kernel(const float* __restrict__ x, __half2* __restrict__ y, int n4) {
    int i = blockIdx.x * blockDim.x + threadIdx.x;
    if (i >= n4) return;
    float4 v = reinterpret_cast<const float4*>(x)[i];
    y[2 * i + 0] = __floats2half2_rn(v.x, v.y);
    y[2 * i + 1] = __floats2half2_rn(v.z, v.w);
}

// ---- pull SpMM, fp16 gather table: one wave per row, 32 lanes x half2 per
// edge; each half-wave keeps 4 edges in flight (8 gathers/wave outstanding).
// out[row] += (w[f]/4)*acc fused. ----
template <bool LAST>
__global__ void spmm_f16_kernel(const int* __restrict__ rlo, const int* __restrict__ rhi,
                                const float2* __restrict__ cs, const __half2* __restrict__ x,
                                __half2* __restrict__ y, float* __restrict__ out,
                                const float* __restrict__ w, int f, int nrows) {
    int gid = blockIdx.x * blockDim.x + threadIdx.x;
    int row = gid >> 6;
    int lane = gid & 63;
    if (row >= nrows) return;
    int s = rlo[row], e = rhi[row];
    int half = lane >> 5, sub = lane & 31;
    float ax0 = 0.f, ay0 = 0.f, ax1 = 0.f, ay1 = 0.f;
    float ax2 = 0.f, ay2 = 0.f, ax3 = 0.f, ay3 = 0.f;
    int k = s + half;
    for (; k + 6 < e; k += 8) {
        float2 e0 = cs[k];
        float2 e1 = cs[k + 2];
        float2 e2 = cs[k + 4];
        float2 e3 = cs[k + 6];
        __half2 h0 = x[((size_t)__float_as_int(e0.x) << 5) + sub];
        __half2 h1 = x[((size_t)__float_as_int(e1.x) << 5) + sub];
        __half2 h2 = x[((size_t)__float_as_int(e2.x) << 5) + sub];
        __half2 h3 = x[((size_t)__float_as_int(e3.x) << 5) + sub];
        float2 f0 = __half22float2(h0);
        float2 f1 = __half22float2(h1);
        float2 f2 = __half22float2(h2);
        float2 f3 = __half22float2(h3);
        ax0 += e0.y * f0.x; ay0 += e0.y * f0.y;
        ax1 += e1.y * f1.x; ay1 += e1.y * f1.y;
        ax2 += e2.y * f2.x; ay2 += e2.y * f2.y;
        ax3 += e3.y * f3.x; ay3 += e3.y * f3.y;
    }
    for (; k < e; k += 2) {
        float2 e0 = cs[k];
        __half2 h0 = x[((size_t)__float_as_int(e0.x) << 5) + sub];
        float2 f0 = __half22float2(h0);
        ax0 += e0.y * f0.x; ay0 += e0.y * f0.y;
    }
    float ax = (ax0 + ax1) + (ax2 + ax3);
    float ay = (ay0 + ay1) + (ay2 + ay3);
    ax += __shfl_xor(ax, 32);
    ay += __shfl_xor(ay, 32);
    if (half == 0) {
        size_t o = ((size_t)row << 5) + sub;
        if (!LAST) y[o] = __floats2half2_rn(ax, ay);
        float c = w[f] * 0.25f;
        float2* o2 = reinterpret_cast<float2*>(out);
        float2 cv = o2[o];
        cv.x += c * ax;
        cv.y += c * ay;
        o2[o] = cv;
    }
}

extern "C" void kernel_launch(void* const* d_in, const int* in_sizes, int n_in,
                              void* d_out, int out_size, void* d_ws, size_t ws_size,
                              hipStream_t stream) {
    const float* emb[3]  = {(const float*)d_in[0], (const float*)d_in[1], (const float*)d_in[2]};
    const int*   gidx[3] = {(const int*)d_in[3],   (const int*)d_in[5],   (const int*)d_in[7]};
    const float* gval[3] = {(const float*)d_in[4], (const float*)d_in[6], (const float*)d_in[8]};
    const float* w = (const float*)d_in[9];
    float* out = (float*)d_out;

    const int nnz = in_sizes[4];
    const size_t bufElems = (size_t)N_TOTAL * DIM;       // 9.6M
    const size_t f16Bytes = bufElems * 2;                // 19.2 MB

    // ws layout:
    //   [0, 38.4MB)      binned (uint2)  -- aliased with {emb16, bufA16}
    //   [38.4, 57.6MB)   bufB16
    //   [57.6, 96MB)     cs (float2)
    //   then rlo, rhi, bcnt, bbase, bcur, bsum
    char* base = (char*)d_ws;
    uint2*   binned = (uint2*)base;
    __half2* emb16  = (__half2*)base;                    // alias: live after scatterc
    __half2* bufA16 = (__half2*)(base + f16Bytes);       // alias: live after spmm layer 1
    __half2* bufB16 = (__half2*)(base + 2 * f16Bytes);
    float2*  cs     = (float2*)(base + 3 * f16Bytes);
    int*     rlo    = (int*)(base + 3 * f16Bytes + (size_t)nnz * 8);
    int*     rhi    = rlo + N_TOTAL;
    int*     bcnt   = rhi + N_TOTAL;
    int*     bbase  = bcnt + NBUCK;        // NBUCK+1
    int*     bcur   = bbase + NBUCK + 1;
    int*     bsum   = bcur + NBUCK;

    const int n4 = (int)(bufElems / 4);
    dim3 eltGrid((n4 + 255) / 256);
    dim3 chunkGrid((nnz + CHUNK - 1) / CHUNK);            // 586
    dim3 rowGrid((unsigned)(((size_t)N_TOTAL * 64 + 255) / 256));

    // layer-0 contributions of all factors in one pass
    init_out_kernel<<<eltGrid, 256, 0, stream>>>(emb[0], emb[1], emb[2], w, out, n4);

    for (int f = 0; f < 3; ++f) {
        // --- bucket CSR build ---
        hipMemsetAsync(bcnt, 0, NBUCK * sizeof(int), stream);
        bucket_hist_kernel<<<chunkGrid, 512, 0, stream>>>(gidx[f], bcnt, nnz);
        scan_block_kernel<<<1, 256, 0, stream>>>(bcnt, bbase, bsum, NBUCK);
        binit_kernel<<<3, 256, 0, stream>>>(bbase, bcur, nnz);
        bin_kernel<<<chunkGrid, 512, 0, stream>>>(gidx[f], gval[f], bcur, binned, nnz);
        scatterc_kernel<<<NBUCK, 256, 0, stream>>>(binned, bbase, rlo, rhi, cs);

        // --- fp16 copy of this factor's embedding (binned is dead now) ---
        conv_f16_kernel<<<eltGrid, 256, 0, stream>>>(emb[f], emb16, n4);

        // --- 3 propagation layers, axpy fused into SpMM epilogue ---
        spmm_f16_kernel<false><<<rowGrid, 256, 0, stream>>>(rlo, rhi, cs, emb16, bufA16,
                                                            out, w, f, N_TOTAL);
        spmm_f16_kernel<false><<<rowGrid, 256, 0, stream>>>(rlo, rhi, cs, bufA16, bufB16,
                                                            out, w, f, N_TOTAL);
        spmm_f16_kernel<true><<<rowGrid, 256, 0, stream>>>(rlo, rhi, cs, bufB16, nullptr,
                                                           out, w, f, N_TOTAL);
    }
}